// Round 3
// baseline (2213.786 us; speedup 1.0000x reference)
//
#include <hip/hip_runtime.h>
#include <stdint.h>

#define N_NODES 100000
#define N_EDGES 600000
#define DMODEL  128
#define NLAYERS 4
#define NGRAPH  128
#define NCLASS  10
#define BN_EPS  1e-5f

// ---------------- zero-init scratch regions we accumulate into ----------------
__global__ void k_zero(int* __restrict__ deg, float* __restrict__ stats,
                       int* __restrict__ gcount) {
  int i = blockIdx.x * 256 + threadIdx.x;
  if (i < N_NODES) deg[i] = 0;
  if (i < NLAYERS * 2 * 2 * DMODEL) stats[i] = 0.0f;
  if (i < NGRAPH) gcount[i] = 0;
}

// ---------------- embedding gather: h[i,d] = emb[x[i],d] ----------------
__global__ void k_embed(const int* __restrict__ x, const float* __restrict__ emb,
                        float* __restrict__ h) {
  int idx = blockIdx.x * 256 + threadIdx.x;
  if (idx >= N_NODES * DMODEL) return;
  int i = idx >> 7;
  int d = idx & 127;
  h[idx] = emb[(size_t)x[i] * DMODEL + d];
}

// ---------------- CSR build ----------------
__global__ void k_hist(const int* __restrict__ dst, int* __restrict__ deg) {
  int e = blockIdx.x * 256 + threadIdx.x;
  if (e < N_EDGES) atomicAdd(&deg[dst[e]], 1);
}

__global__ void k_scan1(const int* __restrict__ deg, int* __restrict__ out,
                        int* __restrict__ bsum, int n) {
  __shared__ int lds[256];
  int t = threadIdx.x;
  int idx = blockIdx.x * 256 + t;
  int v = (idx < n) ? deg[idx] : 0;
  int val = v;
  lds[t] = val;
  for (int ofs = 1; ofs < 256; ofs <<= 1) {
    __syncthreads();
    int u = (t >= ofs) ? lds[t - ofs] : 0;
    __syncthreads();
    val += u;
    lds[t] = val;
  }
  if (idx < n) out[idx] = val - v;           // exclusive within chunk
  if (t == 255) bsum[blockIdx.x] = val;      // chunk total
}

__global__ void k_scan2(const int* __restrict__ bsum, int* __restrict__ bsumx, int nb) {
  __shared__ int lds[512];
  int t = threadIdx.x;
  int v = (t < nb) ? bsum[t] : 0;
  int val = v;
  lds[t] = val;
  for (int ofs = 1; ofs < 512; ofs <<= 1) {
    __syncthreads();
    int u = (t >= ofs) ? lds[t - ofs] : 0;
    __syncthreads();
    val += u;
    lds[t] = val;
  }
  if (t < nb) bsumx[t] = val - v;
}

__global__ void k_scan3(int* __restrict__ row_start, int* __restrict__ cursor,
                        const int* __restrict__ bsumx, int n, int total) {
  int idx = blockIdx.x * 256 + threadIdx.x;
  if (idx < n) {
    int v = row_start[idx] + bsumx[blockIdx.x];
    row_start[idx] = v;
    cursor[idx] = v;
  }
  if (idx == 0) row_start[n] = total;
}

__global__ void k_scatter(const int* __restrict__ ei, const float* __restrict__ ea,
                          int* __restrict__ cursor, int* __restrict__ csr_src,
                          float* __restrict__ ca0, float* __restrict__ ca1) {
  int e = blockIdx.x * 256 + threadIdx.x;
  if (e >= N_EDGES) return;
  int s = ei[e];
  int d = ei[N_EDGES + e];
  int pos = atomicAdd(&cursor[d], 1);
  csr_src[pos] = s;
  ca0[pos] = ea[2 * e];
  ca1[pos] = ea[2 * e + 1];
}

// ------- message + aggregate: z = act(h_i) + sum_in relu(act(h_src) + edge_lin) -----
// act(h) = relu(s*h + t) when hasT (deferred BN+relu of previous layer), else identity.
__global__ void __launch_bounds__(128) k_agg(
    const float* __restrict__ h, const int* __restrict__ row_start,
    const int* __restrict__ csr_src, const float* __restrict__ ca0,
    const float* __restrict__ ca1,
    const float* __restrict__ ew,   // edge_w + l*2*D
    const float* __restrict__ ebp,  // edge_b + l*D
    const float* __restrict__ sIn, const float* __restrict__ tIn, int hasT,
    float* __restrict__ z) {
  int i = blockIdx.x;
  int d = threadIdx.x;
  float ew0 = ew[d];
  float ew1 = ew[DMODEL + d];
  float eb = ebp[d];
  float s = 1.0f;
  float t = 0.0f;
  if (hasT) {
    s = sIn[d];
    t = tIn[d];
  }
  float raw = h[(size_t)i * DMODEL + d];
  float acc = hasT ? fmaxf(s * raw + t, 0.0f) : raw;   // the self term h_i
  int j0 = row_start[i];
  int j1 = row_start[i + 1];
  for (int j = j0; j < j1; ++j) {
    int src = csr_src[j];
    float a0 = ca0[j];
    float a1 = ca1[j];
    float r2 = h[(size_t)src * DMODEL + d];
    float hs = hasT ? fmaxf(s * r2 + t, 0.0f) : r2;
    float m = hs + a0 * ew0 + a1 * ew1 + eb;
    acc += fmaxf(m, 0.0f);
  }
  z[(size_t)i * DMODEL + d] = acc;
}

// ---------------- GEMM: Y = act(X) @ W + bias, plus column sum/sumsq of Y ----------
// act(x) = relu(sIn[k]*x + tIn[k]) when applyIn, else identity (per-K transform).
// X:[N,128] f32 rowmajor, W:[128][128] rowmajor (k-major). Block: 256 threads,
// tile 64 rows x 128 cols, thread = (ty,tx) 16x16, computes 4 rows x 8 cols
// (cols tx+16j, conflict-free LDS). W staged in 64KB LDS.
__global__ void __launch_bounds__(256) k_gemm(
    const float* __restrict__ X, const float* __restrict__ W,
    const float* __restrict__ bias,
    const float* __restrict__ sIn, const float* __restrict__ tIn, int applyIn,
    float* __restrict__ Y,
    float* __restrict__ statsum, float* __restrict__ statsq) {
  __shared__ float wlds[DMODEL * DMODEL];   // 64 KB
  int tid = threadIdx.x;

  for (int i = tid * 4; i < DMODEL * DMODEL; i += 1024) {
    float4 wv = *(const float4*)(W + i);
    wlds[i + 0] = wv.x;
    wlds[i + 1] = wv.y;
    wlds[i + 2] = wv.z;
    wlds[i + 3] = wv.w;
  }
  __syncthreads();

  int tx = tid & 15;
  int ty = tid >> 4;
  int row0 = blockIdx.x * 64 + ty * 4;

  float acc[4][8];
#pragma unroll
  for (int r = 0; r < 4; ++r)
#pragma unroll
    for (int j = 0; j < 8; ++j) acc[r][j] = 0.0f;

  for (int k4 = 0; k4 < DMODEL; k4 += 4) {
    float sv[4], tv[4];
    if (applyIn) {
#pragma unroll
      for (int c = 0; c < 4; ++c) {
        sv[c] = sIn[k4 + c];
        tv[c] = tIn[k4 + c];
      }
    }
    float a[4][4];
#pragma unroll
    for (int r = 0; r < 4; ++r) {
      int row = row0 + r;
      if (row < N_NODES) {
        float4 av = *(const float4*)(X + (size_t)row * DMODEL + k4);
        a[r][0] = av.x;
        a[r][1] = av.y;
        a[r][2] = av.z;
        a[r][3] = av.w;
      } else {
        a[r][0] = a[r][1] = a[r][2] = a[r][3] = 0.0f;
      }
      if (applyIn) {
#pragma unroll
        for (int c = 0; c < 4; ++c) a[r][c] = fmaxf(sv[c] * a[r][c] + tv[c], 0.0f);
      }
    }
#pragma unroll
    for (int kk = 0; kk < 4; ++kk) {
      float wv[8];
#pragma unroll
      for (int j = 0; j < 8; ++j) wv[j] = wlds[(k4 + kk) * DMODEL + tx + 16 * j];
#pragma unroll
      for (int r = 0; r < 4; ++r)
#pragma unroll
        for (int j = 0; j < 8; ++j) acc[r][j] += a[r][kk] * wv[j];
    }
  }

  // epilogue: bias, store, column stats via LDS reduction (reuse wlds[0..255])
  __syncthreads();
  wlds[tid] = 0.0f;
  __syncthreads();

#pragma unroll
  for (int j = 0; j < 8; ++j) {
    int c = tx + 16 * j;
    float bc = bias[c];
    float s = 0.0f;
    float q = 0.0f;
#pragma unroll
    for (int r = 0; r < 4; ++r) {
      int row = row0 + r;
      if (row < N_NODES) {
        float v = acc[r][j] + bc;
        Y[(size_t)row * DMODEL + c] = v;
        s += v;
        q += v * v;
      }
    }
    atomicAdd(&wlds[c], s);
    atomicAdd(&wlds[DMODEL + c], q);
  }
  __syncthreads();
  if (tid < DMODEL) {
    atomicAdd(&statsum[tid], wlds[tid]);
  } else {
    atomicAdd(&statsq[tid - DMODEL], wlds[tid]);
  }
}

// ---------------- fold stats into BN scale/shift ----------------
__global__ void k_bnfin(const float* __restrict__ statsum, const float* __restrict__ statsq,
                        const float* __restrict__ gamma, const float* __restrict__ beta,
                        float* __restrict__ sOut, float* __restrict__ tOut) {
  int d = threadIdx.x;
  float mean = statsum[d] * (1.0f / N_NODES);
  float var = statsq[d] * (1.0f / N_NODES) - mean * mean;
  float inv = rsqrtf(var + BN_EPS);
  float s = gamma[d] * inv;
  sOut[d] = s;
  tOut[d] = beta[d] - mean * s;
}

// ---------------- pooling ----------------
__global__ void k_gcount(const int* __restrict__ batch, int* __restrict__ gcount) {
  int i = blockIdx.x * 256 + threadIdx.x;
  if (i < N_NODES) atomicAdd(&gcount[batch[i]], 1);
}

__global__ void k_gscan(const int* __restrict__ gcount, int* __restrict__ gstart) {
  __shared__ int lds[NGRAPH];
  int t = threadIdx.x;
  int v = gcount[t];
  int val = v;
  lds[t] = val;
  for (int ofs = 1; ofs < NGRAPH; ofs <<= 1) {
    __syncthreads();
    int u = (t >= ofs) ? lds[t - ofs] : 0;
    __syncthreads();
    val += u;
    lds[t] = val;
  }
  gstart[t] = val - v;
  if (t == NGRAPH - 1) gstart[NGRAPH] = val;
}

// applies deferred final BN affine (no relu — last layer has none)
__global__ void k_pool(const float* __restrict__ h, const int* __restrict__ gstart,
                       const float* __restrict__ s2, const float* __restrict__ t2,
                       float* __restrict__ pooled) {
  int g = blockIdx.x;
  int d = threadIdx.x;
  int i0 = gstart[g];
  int i1 = gstart[g + 1];
  float s = s2[d];
  float t = t2[d];
  float acc = 0.0f;
  for (int i = i0; i < i1; ++i) acc += s * h[(size_t)i * DMODEL + d] + t;
  int cnt = i1 - i0;
  pooled[g * DMODEL + d] = acc / (float)(cnt > 0 ? cnt : 1);
}

// ---------------- classifier ----------------
__global__ void k_classifier(const float* __restrict__ pooled,
                             const float* __restrict__ cw1, const float* __restrict__ cb1,
                             const float* __restrict__ cw2, const float* __restrict__ cb2,
                             float* __restrict__ out) {
  __shared__ float pl[DMODEL];
  __shared__ float hid[DMODEL];
  int g = blockIdx.x;
  int d = threadIdx.x;
  pl[d] = pooled[g * DMODEL + d];
  __syncthreads();
  float acc = cb1[d];
  for (int k = 0; k < DMODEL; ++k) acc += pl[k] * cw1[k * DMODEL + d];
  hid[d] = fmaxf(acc, 0.0f);
  __syncthreads();
  if (d < NCLASS) {
    float acc2 = cb2[d];
    for (int k = 0; k < DMODEL; ++k) acc2 += hid[k] * cw2[k * NCLASS + d];
    out[g * NCLASS + d] = acc2;
  }
}

// ---------------- launcher ----------------
extern "C" void kernel_launch(void* const* d_in, const int* in_sizes, int n_in,
                              void* d_out, int out_size, void* d_ws, size_t ws_size,
                              hipStream_t stream) {
  const int*   x      = (const int*)d_in[0];
  const int*   ei     = (const int*)d_in[1];
  const float* ea     = (const float*)d_in[2];
  const int*   batch  = (const int*)d_in[3];
  const float* emb    = (const float*)d_in[4];
  const float* edge_w = (const float*)d_in[5];
  const float* edge_b = (const float*)d_in[6];
  const float* w1     = (const float*)d_in[7];
  const float* b1     = (const float*)d_in[8];
  const float* g1     = (const float*)d_in[9];
  const float* beta1  = (const float*)d_in[10];
  const float* w2     = (const float*)d_in[11];
  const float* b2     = (const float*)d_in[12];
  const float* ng     = (const float*)d_in[13];
  const float* nb     = (const float*)d_in[14];
  const float* cw1    = (const float*)d_in[15];
  const float* cb1    = (const float*)d_in[16];
  const float* cw2    = (const float*)d_in[17];
  const float* cb2    = (const float*)d_in[18];

  char* ws = (char*)d_ws;
  size_t off = 0;
  auto alloc = [&](size_t bytes) -> void* {
    void* p = ws + off;
    off += (bytes + 255) & ~(size_t)255;
    return p;
  };

  float* h_raw     = (float*)alloc((size_t)N_NODES * DMODEL * sizeof(float));
  float* z         = (float*)alloc((size_t)N_NODES * DMODEL * sizeof(float));
  float* y1        = (float*)alloc((size_t)N_NODES * DMODEL * sizeof(float));
  int*   row_start = (int*)alloc((N_NODES + 1) * sizeof(int));
  int*   cursor    = (int*)alloc(N_NODES * sizeof(int));
  int*   deg       = (int*)alloc(N_NODES * sizeof(int));
  int*   csr_src   = (int*)alloc(N_EDGES * sizeof(int));
  float* ca0       = (float*)alloc(N_EDGES * sizeof(float));
  float* ca1       = (float*)alloc(N_EDGES * sizeof(float));
  float* stats     = (float*)alloc((size_t)NLAYERS * 2 * 2 * DMODEL * sizeof(float));
  float* st        = (float*)alloc((size_t)NLAYERS * 2 * 2 * DMODEL * sizeof(float));
  int*   gcount    = (int*)alloc(NGRAPH * sizeof(int));
  int*   gstart    = (int*)alloc((NGRAPH + 1) * sizeof(int));
  float* pooled    = (float*)alloc((size_t)NGRAPH * DMODEL * sizeof(float));
  int*   bsum      = (int*)alloc(512 * sizeof(int));
  int*   bsumx     = (int*)alloc(512 * sizeof(int));

  auto statSum = [&](int l, int which) { return stats + ((l * 2 + which) * 2 + 0) * DMODEL; };
  auto statSq  = [&](int l, int which) { return stats + ((l * 2 + which) * 2 + 1) * DMODEL; };
  auto sArr    = [&](int l, int which) { return st + ((l * 2 + which) * 2 + 0) * DMODEL; };
  auto tArr    = [&](int l, int which) { return st + ((l * 2 + which) * 2 + 1) * DMODEL; };

  const int nbScan = (N_NODES + 255) / 256;          // 391
  const int nbEdge = (N_EDGES + 255) / 256;          // 2344
  const int nbEmb  = (N_NODES * DMODEL + 255) / 256; // 50000
  const int nbGemm = (N_NODES + 63) / 64;            // 1563

  k_zero<<<nbScan, 256, 0, stream>>>(deg, stats, gcount);
  k_embed<<<nbEmb, 256, 0, stream>>>(x, emb, h_raw);
  k_hist<<<nbEdge, 256, 0, stream>>>(ei + N_EDGES, deg);
  k_scan1<<<nbScan, 256, 0, stream>>>(deg, row_start, bsum, N_NODES);
  k_scan2<<<1, 512, 0, stream>>>(bsum, bsumx, nbScan);
  k_scan3<<<nbScan, 256, 0, stream>>>(row_start, cursor, bsumx, N_NODES, N_EDGES);
  k_scatter<<<nbEdge, 256, 0, stream>>>(ei, ea, cursor, csr_src, ca0, ca1);

  for (int l = 0; l < NLAYERS; ++l) {
    const float* sI = (l > 0) ? sArr(l - 1, 1) : (const float*)nullptr;
    const float* tI = (l > 0) ? tArr(l - 1, 1) : (const float*)nullptr;
    k_agg<<<N_NODES, 128, 0, stream>>>(h_raw, row_start, csr_src, ca0, ca1,
                                       edge_w + (size_t)l * 2 * DMODEL,
                                       edge_b + (size_t)l * DMODEL,
                                       sI, tI, (l > 0) ? 1 : 0, z);
    // y1 = z @ w1[l] + b1[l]  (stats -> BN1)
    k_gemm<<<nbGemm, 256, 0, stream>>>(
        z, w1 + (size_t)l * DMODEL * DMODEL, b1 + (size_t)l * DMODEL,
        (const float*)nullptr, (const float*)nullptr, 0,
        y1, statSum(l, 0), statSq(l, 0));
    k_bnfin<<<1, DMODEL, 0, stream>>>(statSum(l, 0), statSq(l, 0),
                                      g1 + (size_t)l * DMODEL, beta1 + (size_t)l * DMODEL,
                                      sArr(l, 0), tArr(l, 0));
    // h_raw = relu(BN1(y1)) @ w2[l] + b2[l]  (stats -> BN2, applied by next consumer)
    k_gemm<<<nbGemm, 256, 0, stream>>>(
        y1, w2 + (size_t)l * DMODEL * DMODEL, b2 + (size_t)l * DMODEL,
        sArr(l, 0), tArr(l, 0), 1,
        h_raw, statSum(l, 1), statSq(l, 1));
    k_bnfin<<<1, DMODEL, 0, stream>>>(statSum(l, 1), statSq(l, 1),
                                      ng + (size_t)l * DMODEL, nb + (size_t)l * DMODEL,
                                      sArr(l, 1), tArr(l, 1));
  }

  k_gcount<<<nbScan, 256, 0, stream>>>(batch, gcount);
  k_gscan<<<1, NGRAPH, 0, stream>>>(gcount, gstart);
  k_pool<<<NGRAPH, DMODEL, 0, stream>>>(h_raw, gstart, sArr(NLAYERS - 1, 1),
                                        tArr(NLAYERS - 1, 1), pooled);
  k_classifier<<<NGRAPH, DMODEL, 0, stream>>>(pooled, cw1, cb1, cw2, cb2, (float*)d_out);
}

// Round 4
// 1144.675 us; speedup vs baseline: 1.9340x; 1.9340x over previous
//
#include <hip/hip_runtime.h>
#include <stdint.h>

#define N_NODES 100000
#define N_EDGES 600000
#define DMODEL  128
#define NLAYERS 4
#define NGRAPH  128
#define NCLASS  10
#define BN_EPS  1e-5f
#define NSLOT   32     // stat partial slots (atomic contention spreading)

typedef __bf16 bf16x8 __attribute__((ext_vector_type(8)));
typedef float  f32x4  __attribute__((ext_vector_type(4)));

// ---------------- zero-init scratch we accumulate into ----------------
__global__ void k_zero(int* __restrict__ deg, float* __restrict__ statpart,
                       float* __restrict__ psum) {
  int i = blockIdx.x * 256 + threadIdx.x;
  if (i < N_NODES) deg[i] = 0;
  if (i < NSLOT * 2 * DMODEL) statpart[i] = 0.0f;
  if (i < NGRAPH * DMODEL) psum[i] = 0.0f;
}

// ---------------- embedding gather: h[i,d] = emb[x[i],d] ----------------
__global__ void k_embed(const int* __restrict__ x, const float* __restrict__ emb,
                        float* __restrict__ h) {
  int idx = blockIdx.x * 256 + threadIdx.x;
  if (idx >= N_NODES * DMODEL) return;
  int i = idx >> 7;
  int d = idx & 127;
  h[idx] = emb[(size_t)x[i] * DMODEL + d];
}

// ------- transpose + cvt weights: wt[mat][n][k] = bf16(w[mat][k][n]) -------
__global__ void k_cvtw(const float* __restrict__ w1, const float* __restrict__ w2,
                       __bf16* __restrict__ wt) {
  int idx = blockIdx.x * 256 + threadIdx.x;   // L*2*D*D = 131072
  if (idx >= NLAYERS * 2 * DMODEL * DMODEL) return;
  int mat = idx >> 14;
  int rem = idx & 16383;
  int n = rem >> 7;
  int k = rem & 127;
  int l = mat >> 1;
  int which = mat & 1;
  const float* w = which ? w2 : w1;
  wt[idx] = (__bf16)w[(size_t)l * DMODEL * DMODEL + (size_t)k * DMODEL + n];
}

// ---------------- CSR build ----------------
__global__ void k_hist(const int* __restrict__ dst, int* __restrict__ deg) {
  int e = blockIdx.x * 256 + threadIdx.x;
  if (e < N_EDGES) atomicAdd(&deg[dst[e]], 1);
}

__global__ void k_scan1(const int* __restrict__ deg, int* __restrict__ out,
                        int* __restrict__ bsum, int n) {
  __shared__ int lds[256];
  int t = threadIdx.x;
  int idx = blockIdx.x * 256 + t;
  int v = (idx < n) ? deg[idx] : 0;
  int val = v;
  lds[t] = val;
  for (int ofs = 1; ofs < 256; ofs <<= 1) {
    __syncthreads();
    int u = (t >= ofs) ? lds[t - ofs] : 0;
    __syncthreads();
    val += u;
    lds[t] = val;
  }
  if (idx < n) out[idx] = val - v;           // exclusive within chunk
  if (t == 255) bsum[blockIdx.x] = val;      // chunk total
}

__global__ void k_scan2(const int* __restrict__ bsum, int* __restrict__ bsumx, int nb) {
  __shared__ int lds[512];
  int t = threadIdx.x;
  int v = (t < nb) ? bsum[t] : 0;
  int val = v;
  lds[t] = val;
  for (int ofs = 1; ofs < 512; ofs <<= 1) {
    __syncthreads();
    int u = (t >= ofs) ? lds[t - ofs] : 0;
    __syncthreads();
    val += u;
    lds[t] = val;
  }
  if (t < nb) bsumx[t] = val - v;
}

__global__ void k_scan3(int* __restrict__ row_start, int* __restrict__ cursor,
                        const int* __restrict__ bsumx, int n, int total) {
  int idx = blockIdx.x * 256 + threadIdx.x;
  if (idx < n) {
    int v = row_start[idx] + bsumx[blockIdx.x];
    row_start[idx] = v;
    cursor[idx] = v;
  }
  if (idx == 0) row_start[n] = total;
}

__global__ void k_scatter(const int* __restrict__ ei, const float* __restrict__ ea,
                          int* __restrict__ cursor, int* __restrict__ csr_src,
                          float* __restrict__ ca0, float* __restrict__ ca1) {
  int e = blockIdx.x * 256 + threadIdx.x;
  if (e >= N_EDGES) return;
  int s = ei[e];
  int d = ei[N_EDGES + e];
  int pos = atomicAdd(&cursor[d], 1);
  csr_src[pos] = s;
  ca0[pos] = ea[2 * e];
  ca1[pos] = ea[2 * e + 1];
}

// ------- message + aggregate: z = act(h_i) + sum_in relu(act(h_src) + edge_lin) -----
// act(h) = relu(s*h + t) when hasT (deferred BN+relu of previous layer), else identity.
__global__ void __launch_bounds__(128) k_agg(
    const float* __restrict__ h, const int* __restrict__ row_start,
    const int* __restrict__ csr_src, const float* __restrict__ ca0,
    const float* __restrict__ ca1,
    const float* __restrict__ ew,   // edge_w + l*2*D
    const float* __restrict__ ebp,  // edge_b + l*D
    const float* __restrict__ sIn, const float* __restrict__ tIn, int hasT,
    float* __restrict__ z) {
  int i = blockIdx.x;
  int d = threadIdx.x;
  float ew0 = ew[d];
  float ew1 = ew[DMODEL + d];
  float eb = ebp[d];
  float s = 1.0f;
  float t = 0.0f;
  if (hasT) {
    s = sIn[d];
    t = tIn[d];
  }
  float raw = h[(size_t)i * DMODEL + d];
  float acc = hasT ? fmaxf(s * raw + t, 0.0f) : raw;   // the self term h_i
  int j0 = row_start[i];
  int j1 = row_start[i + 1];
  for (int j = j0; j < j1; ++j) {
    int src = csr_src[j];
    float a0 = ca0[j];
    float a1 = ca1[j];
    float r2 = h[(size_t)src * DMODEL + d];
    float hs = hasT ? fmaxf(s * r2 + t, 0.0f) : r2;
    float m = hs + a0 * ew0 + a1 * ew1 + eb;
    acc += fmaxf(m, 0.0f);
  }
  z[(size_t)i * DMODEL + d] = acc;
}

// ---------------- GEMM: Y = act(X) @ W + bias  (bf16 MFMA, f32 storage) ------------
// act(x) = relu(sIn[k]*x + tIn[k]) when applyIn. X:[N,128] f32. Wt:[n][k] bf16.
// 256 thr = 4 waves; wave w: rows blk*64+w*16 .. +15, all 128 cols.
// MFMA 16x16x32 bf16, fragment maps per learn_hip m89/m92:
//   A[m=lane&15][k=(lane>>4)*8+j], B[n=lane&15][k=(lane>>4)*8+j],
//   C/D col=lane&15, row=(lane>>4)*4+reg.
__global__ void __launch_bounds__(256) k_gemm(
    const float* __restrict__ X, const __bf16* __restrict__ Wt,
    const float* __restrict__ bias,
    const float* __restrict__ sIn, const float* __restrict__ tIn, int applyIn,
    float* __restrict__ Y,
    float* __restrict__ statpart) {
  int wave = threadIdx.x >> 6;
  int lane = threadIdx.x & 63;
  int n16 = lane & 15;
  int quad = lane >> 4;
  int m0 = blockIdx.x * 64 + wave * 16;
  int rowA = m0 + n16;

  f32x4 acc[8];
  for (int ct = 0; ct < 8; ++ct)
    for (int r = 0; r < 4; ++r) acc[ct][r] = 0.0f;

  const float* xrow = X + (size_t)rowA * DMODEL;

#pragma unroll
  for (int kk = 0; kk < 4; ++kk) {
    int k0 = kk * 32 + quad * 8;
    bf16x8 a;
    if (rowA < N_NODES) {
      float4 v0 = *(const float4*)(xrow + k0);
      float4 v1 = *(const float4*)(xrow + k0 + 4);
      float f[8];
      f[0] = v0.x; f[1] = v0.y; f[2] = v0.z; f[3] = v0.w;
      f[4] = v1.x; f[5] = v1.y; f[6] = v1.z; f[7] = v1.w;
      if (applyIn) {
#pragma unroll
        for (int j = 0; j < 8; ++j) f[j] = fmaxf(sIn[k0 + j] * f[j] + tIn[k0 + j], 0.0f);
      }
#pragma unroll
      for (int j = 0; j < 8; ++j) a[j] = (__bf16)f[j];
    } else {
#pragma unroll
      for (int j = 0; j < 8; ++j) a[j] = (__bf16)0.0f;
    }
#pragma unroll
    for (int ct = 0; ct < 8; ++ct) {
      bf16x8 b = *(const bf16x8*)(Wt + (size_t)(ct * 16 + n16) * DMODEL + k0);
      acc[ct] = __builtin_amdgcn_mfma_f32_16x16x32_bf16(a, b, acc[ct], 0, 0, 0);
    }
  }

  // epilogue: bias add, f32 store, column stats (wave-level shfl reduce + spread atomics)
  int slot = (blockIdx.x * 4 + wave) & (NSLOT - 1);
#pragma unroll
  for (int ct = 0; ct < 8; ++ct) {
    int c = ct * 16 + n16;
    float bc = bias[c];
    float sum = 0.0f;
    float sq = 0.0f;
#pragma unroll
    for (int r = 0; r < 4; ++r) {
      int row = m0 + quad * 4 + r;
      if (row < N_NODES) {
        float v = acc[ct][r] + bc;
        Y[(size_t)row * DMODEL + c] = v;
        sum += v;
        sq += v * v;
      }
    }
    sum += __shfl_xor(sum, 16);
    sq  += __shfl_xor(sq, 16);
    sum += __shfl_xor(sum, 32);
    sq  += __shfl_xor(sq, 32);
    if (quad == 0) {
      atomicAdd(&statpart[slot * (2 * DMODEL) + c], sum);
      atomicAdd(&statpart[slot * (2 * DMODEL) + DMODEL + c], sq);
    }
  }
}

// ------- fold stat partials into BN scale/shift, and re-zero partials -------
__global__ void k_bnfin(float* __restrict__ statpart,
                        const float* __restrict__ gamma, const float* __restrict__ beta,
                        float* __restrict__ sOut, float* __restrict__ tOut) {
  int d = threadIdx.x;   // 128
  float sum = 0.0f;
  float sq = 0.0f;
  for (int p = 0; p < NSLOT; ++p) {
    sum += statpart[p * (2 * DMODEL) + d];
    sq  += statpart[p * (2 * DMODEL) + DMODEL + d];
  }
  float mean = sum * (1.0f / N_NODES);
  float var = sq * (1.0f / N_NODES) - mean * mean;
  float inv = rsqrtf(var + BN_EPS);
  float s = gamma[d] * inv;
  sOut[d] = s;
  tOut[d] = beta[d] - mean * s;
  for (int p = 0; p < NSLOT; ++p) {
    statpart[p * (2 * DMODEL) + d] = 0.0f;
    statpart[p * (2 * DMODEL) + DMODEL + d] = 0.0f;
  }
}

// ------- graph boundaries by binary search over sorted batch (replaces atomics) -----
__global__ void k_gstart(const int* __restrict__ batch, int* __restrict__ gstart) {
  int g = blockIdx.x * 256 + threadIdx.x;
  if (g > NGRAPH) return;
  int lo = 0;
  int hi = N_NODES;
  while (lo < hi) {
    int mid = (lo + hi) >> 1;
    if (batch[mid] < g) lo = mid + 1; else hi = mid;
  }
  gstart[g] = lo;   // first node with batch >= g; gstart[G] = N
}

// ------- pooling partial sums of raw h (affine deferred to classifier) -------
__global__ void k_pool(const float* __restrict__ h, const int* __restrict__ gstart,
                       float* __restrict__ psum) {
  int g = blockIdx.x;
  int slice = blockIdx.y;   // 0..7
  int d = threadIdx.x;
  int i0 = gstart[g];
  int i1 = gstart[g + 1];
  float acc = 0.0f;
  for (int i = i0 + slice; i < i1; i += 8) acc += h[(size_t)i * DMODEL + d];
  atomicAdd(&psum[g * DMODEL + d], acc);
}

// ------- classifier: applies final BN affine + mean, then Linear-ReLU-Linear -------
__global__ void k_classifier(const float* __restrict__ psum, const int* __restrict__ gstart,
                             const float* __restrict__ s2, const float* __restrict__ t2,
                             const float* __restrict__ cw1, const float* __restrict__ cb1,
                             const float* __restrict__ cw2, const float* __restrict__ cb2,
                             float* __restrict__ out) {
  __shared__ float pl[DMODEL];
  __shared__ float hid[DMODEL];
  int g = blockIdx.x;
  int d = threadIdx.x;
  int cnt = gstart[g + 1] - gstart[g];
  // reference: pooled = sum/max(cnt,1); h already includes BN2 affine there, so:
  pl[d] = (cnt > 0) ? (s2[d] * (psum[g * DMODEL + d] / (float)cnt) + t2[d]) : 0.0f;
  __syncthreads();
  float acc = cb1[d];
  for (int k = 0; k < DMODEL; ++k) acc += pl[k] * cw1[k * DMODEL + d];
  hid[d] = fmaxf(acc, 0.0f);
  __syncthreads();
  if (d < NCLASS) {
    float acc2 = cb2[d];
    for (int k = 0; k < DMODEL; ++k) acc2 += hid[k] * cw2[k * NCLASS + d];
    out[g * NCLASS + d] = acc2;
  }
}

// ---------------- launcher ----------------
extern "C" void kernel_launch(void* const* d_in, const int* in_sizes, int n_in,
                              void* d_out, int out_size, void* d_ws, size_t ws_size,
                              hipStream_t stream) {
  const int*   x      = (const int*)d_in[0];
  const int*   ei     = (const int*)d_in[1];
  const float* ea     = (const float*)d_in[2];
  const int*   batch  = (const int*)d_in[3];
  const float* emb    = (const float*)d_in[4];
  const float* edge_w = (const float*)d_in[5];
  const float* edge_b = (const float*)d_in[6];
  const float* w1     = (const float*)d_in[7];
  const float* b1     = (const float*)d_in[8];
  const float* g1     = (const float*)d_in[9];
  const float* beta1  = (const float*)d_in[10];
  const float* w2     = (const float*)d_in[11];
  const float* b2     = (const float*)d_in[12];
  const float* ng     = (const float*)d_in[13];
  const float* nb     = (const float*)d_in[14];
  const float* cw1    = (const float*)d_in[15];
  const float* cb1    = (const float*)d_in[16];
  const float* cw2    = (const float*)d_in[17];
  const float* cb2    = (const float*)d_in[18];

  char* ws = (char*)d_ws;
  size_t off = 0;
  auto alloc = [&](size_t bytes) -> void* {
    void* p = ws + off;
    off += (bytes + 255) & ~(size_t)255;
    return p;
  };

  float*  h_raw     = (float*)alloc((size_t)N_NODES * DMODEL * sizeof(float));
  float*  z         = (float*)alloc((size_t)N_NODES * DMODEL * sizeof(float));
  float*  y1        = (float*)alloc((size_t)N_NODES * DMODEL * sizeof(float));
  int*    row_start = (int*)alloc((N_NODES + 1) * sizeof(int));
  int*    cursor    = (int*)alloc(N_NODES * sizeof(int));
  int*    deg       = (int*)alloc(N_NODES * sizeof(int));
  int*    csr_src   = (int*)alloc(N_EDGES * sizeof(int));
  float*  ca0       = (float*)alloc(N_EDGES * sizeof(float));
  float*  ca1       = (float*)alloc(N_EDGES * sizeof(float));
  __bf16* wt        = (__bf16*)alloc((size_t)NLAYERS * 2 * DMODEL * DMODEL * sizeof(__bf16));
  float*  statpart  = (float*)alloc((size_t)NSLOT * 2 * DMODEL * sizeof(float));
  float*  st        = (float*)alloc((size_t)NLAYERS * 2 * 2 * DMODEL * sizeof(float));
  int*    gstart    = (int*)alloc((NGRAPH + 1) * sizeof(int));
  float*  psum      = (float*)alloc((size_t)NGRAPH * DMODEL * sizeof(float));
  int*    bsum      = (int*)alloc(512 * sizeof(int));
  int*    bsumx     = (int*)alloc(512 * sizeof(int));

  auto sArr = [&](int l, int which) { return st + ((l * 2 + which) * 2 + 0) * DMODEL; };
  auto tArr = [&](int l, int which) { return st + ((l * 2 + which) * 2 + 1) * DMODEL; };

  const int nbScan = (N_NODES + 255) / 256;          // 391
  const int nbEdge = (N_EDGES + 255) / 256;          // 2344
  const int nbEmb  = (N_NODES * DMODEL + 255) / 256; // 50000
  const int nbGemm = (N_NODES + 63) / 64;            // 1563

  k_zero<<<nbScan, 256, 0, stream>>>(deg, statpart, psum);
  k_embed<<<nbEmb, 256, 0, stream>>>(x, emb, h_raw);
  k_cvtw<<<(NLAYERS * 2 * DMODEL * DMODEL) / 256, 256, 0, stream>>>(w1, w2, wt);
  k_hist<<<nbEdge, 256, 0, stream>>>(ei + N_EDGES, deg);
  k_scan1<<<nbScan, 256, 0, stream>>>(deg, row_start, bsum, N_NODES);
  k_scan2<<<1, 512, 0, stream>>>(bsum, bsumx, nbScan);
  k_scan3<<<nbScan, 256, 0, stream>>>(row_start, cursor, bsumx, N_NODES, N_EDGES);
  k_scatter<<<nbEdge, 256, 0, stream>>>(ei, ea, cursor, csr_src, ca0, ca1);
  k_gstart<<<1, 256, 0, stream>>>(batch, gstart);

  for (int l = 0; l < NLAYERS; ++l) {
    const float* sI = (l > 0) ? sArr(l - 1, 1) : (const float*)nullptr;
    const float* tI = (l > 0) ? tArr(l - 1, 1) : (const float*)nullptr;
    k_agg<<<N_NODES, 128, 0, stream>>>(h_raw, row_start, csr_src, ca0, ca1,
                                       edge_w + (size_t)l * 2 * DMODEL,
                                       edge_b + (size_t)l * DMODEL,
                                       sI, tI, (l > 0) ? 1 : 0, z);
    // y1 = z @ w1[l] + b1[l]   (stats -> BN1)
    k_gemm<<<nbGemm, 256, 0, stream>>>(
        z, wt + (size_t)(l * 2 + 0) * DMODEL * DMODEL, b1 + (size_t)l * DMODEL,
        (const float*)nullptr, (const float*)nullptr, 0,
        y1, statpart);
    k_bnfin<<<1, DMODEL, 0, stream>>>(statpart,
                                      g1 + (size_t)l * DMODEL, beta1 + (size_t)l * DMODEL,
                                      sArr(l, 0), tArr(l, 0));
    // h_raw = relu(BN1(y1)) @ w2[l] + b2[l]   (stats -> BN2, applied by next consumer)
    k_gemm<<<nbGemm, 256, 0, stream>>>(
        y1, wt + (size_t)(l * 2 + 1) * DMODEL * DMODEL, b2 + (size_t)l * DMODEL,
        sArr(l, 0), tArr(l, 0), 1,
        h_raw, statpart);
    k_bnfin<<<1, DMODEL, 0, stream>>>(statpart,
                                      ng + (size_t)l * DMODEL, nb + (size_t)l * DMODEL,
                                      sArr(l, 1), tArr(l, 1));
  }

  dim3 poolGrid(NGRAPH, 8);
  k_pool<<<poolGrid, DMODEL, 0, stream>>>(h_raw, gstart, psum);
  k_classifier<<<NGRAPH, DMODEL, 0, stream>>>(psum, gstart, sArr(NLAYERS - 1, 1),
                                              tArr(NLAYERS - 1, 1),
                                              cw1, cb1, cw2, cb2, (float*)d_out);
}